// Round 3
// baseline (341.807 us; speedup 1.0000x reference)
//
#include <hip/hip_runtime.h>
#include <math.h>

// FFF sparse tree forward. B=16384, D_IN=D_OUT=768, DEPTH=11, n_nodes=4095.
//
// One wave per TWO samples; lane owns 12 dims of each (3x float4, lane+j*64).
// The two samples' serial chains (gather W1[node] -> f64 dot -> butterfly ->
// sign) are interleaved in one wave: independent dep chains overlap, and the
// off-chain work (exact-erf GELU + w2 fma) is placed AFTER issuing the next
// level's W1 gathers so it hides their latency.
//
// amdgpu_waves_per_eu(4,4) pins the allocator at the 128-VGPR / 4-waves-per-EU
// point: R2 showed the default heuristic squeezing to 64 VGPRs and spilling
// ~540 MB of scratch (WRITE_SIZE 589 MB, dur 2.5x worse).

#define FFF_LVLS 12        // depth+1
#define FFF_D 768
#define FFF_NF4 3          // float4 per lane per row
#define FFF_ROWF4 192      // float4 per 768-f32 row

__device__ __forceinline__ float gelu_exact(float v) {
    return 0.5f * v * (1.0f + erff(v * 0.70710678118654752440f));
}

__device__ __forceinline__ double dot12_f64(const float4* xv, const float4* a) {
    double p0 = 0.0, p1 = 0.0;
#pragma unroll
    for (int j = 0; j < FFF_NF4; ++j) {
        p0 += (double)xv[j].x * (double)a[j].x;
        p1 += (double)xv[j].y * (double)a[j].y;
        p0 += (double)xv[j].z * (double)a[j].z;
        p1 += (double)xv[j].w * (double)a[j].w;
    }
    return p0 + p1;
}

__global__ __launch_bounds__(256)
__attribute__((amdgpu_waves_per_eu(4, 4)))
void fff_sparse_kernel(
    const float* __restrict__ x,
    const float* __restrict__ w1s,
    const float* __restrict__ w2s,
    float* __restrict__ out,
    int B)
{
    const int wave = threadIdx.x >> 6;
    const int lane = threadIdx.x & 63;
    const int wid = blockIdx.x * 4 + wave;
    const int b0 = wid * 2;
    const int b1 = b0 + 1;
    if (b1 >= B) return;   // grid sized exactly for even B

    const float4* __restrict__ xf4  = (const float4*)x;
    const float4* __restrict__ w1f4 = (const float4*)w1s;
    const float4* __restrict__ w2f4 = (const float4*)w2s;

    // x rows in registers, coalesced.
    float4 xv0[FFF_NF4], xv1[FFF_NF4];
    {
        const int xb0 = b0 * FFF_ROWF4 + lane;
        const int xb1 = b1 * FFF_ROWF4 + lane;
#pragma unroll
        for (int j = 0; j < FFF_NF4; ++j) xv0[j] = xf4[xb0 + j * 64];
#pragma unroll
        for (int j = 0; j < FFF_NF4; ++j) xv1[j] = xf4[xb1 + j * 64];
    }

    float4 acc0[FFF_NF4], acc1[FFF_NF4];
#pragma unroll
    for (int j = 0; j < FFF_NF4; ++j) {
        acc0[j] = make_float4(0.f, 0.f, 0.f, 0.f);
        acc1[j] = make_float4(0.f, 0.f, 0.f, 0.f);
    }

    int node0 = 0, node1 = 0;

    // Prologue: root W1 + w2 rows for both samples.
    float4 a0[FFF_NF4], a1[FFF_NF4], c0[FFF_NF4], c1[FFF_NF4];
#pragma unroll
    for (int j = 0; j < FFF_NF4; ++j) a0[j] = w1f4[lane + j * 64];
#pragma unroll
    for (int j = 0; j < FFF_NF4; ++j) a1[j] = w1f4[lane + j * 64];
#pragma unroll
    for (int j = 0; j < FFF_NF4; ++j) c0[j] = w2f4[lane + j * 64];
#pragma unroll
    for (int j = 0; j < FFF_NF4; ++j) c1[j] = w2f4[lane + j * 64];

#pragma unroll
    for (int lvl = 0; lvl < FFF_LVLS; ++lvl) {
        // Two independent f64 dots + interleaved butterflies: the two
        // dependency chains overlap in the pipeline.
        double p0 = dot12_f64(xv0, a0);
        double p1 = dot12_f64(xv1, a1);
#pragma unroll
        for (int m = 32; m > 0; m >>= 1) {
            p0 += __shfl_xor(p0, m, 64);
            p1 += __shfl_xor(p1, m, 64);
        }

        // Routing decision (wave-uniform scalar).
        const int s0 = __builtin_amdgcn_readfirstlane(p0 >= 0.0 ? 1 : 0);
        const int s1 = __builtin_amdgcn_readfirstlane(p1 >= 0.0 ? 1 : 0);
        node0 = 2 * node0 + 1 + s0;
        node1 = 2 * node1 + 1 + s1;

        // Issue next level's W1 gathers IMMEDIATELY (latency-critical);
        // the GELU + w2 accumulation below overlaps their flight time.
        float4 na0[FFF_NF4], na1[FFF_NF4];
        if (lvl + 1 < FFF_LVLS) {
            const int r0 = node0 * FFF_ROWF4 + lane;
            const int r1 = node1 * FFF_ROWF4 + lane;
#pragma unroll
            for (int j = 0; j < FFF_NF4; ++j) na0[j] = w1f4[r0 + j * 64];
#pragma unroll
            for (int j = 0; j < FFF_NF4; ++j) na1[j] = w1f4[r1 + j * 64];
        }

        // Off-chain: exact GELU + accumulate current level's w2 rows.
        const float act0 = gelu_exact((float)p0);
        const float act1 = gelu_exact((float)p1);
#pragma unroll
        for (int j = 0; j < FFF_NF4; ++j) {
            acc0[j].x = fmaf(act0, c0[j].x, acc0[j].x);
            acc0[j].y = fmaf(act0, c0[j].y, acc0[j].y);
            acc0[j].z = fmaf(act0, c0[j].z, acc0[j].z);
            acc0[j].w = fmaf(act0, c0[j].w, acc0[j].w);
            acc1[j].x = fmaf(act1, c1[j].x, acc1[j].x);
            acc1[j].y = fmaf(act1, c1[j].y, acc1[j].y);
            acc1[j].z = fmaf(act1, c1[j].z, acc1[j].z);
            acc1[j].w = fmaf(act1, c1[j].w, acc1[j].w);
        }

        // Next level's w2 rows: a whole level of slack before use.
        if (lvl + 1 < FFF_LVLS) {
            const int r0 = node0 * FFF_ROWF4 + lane;
            const int r1 = node1 * FFF_ROWF4 + lane;
            float4 nc0[FFF_NF4], nc1[FFF_NF4];
#pragma unroll
            for (int j = 0; j < FFF_NF4; ++j) nc0[j] = w2f4[r0 + j * 64];
#pragma unroll
            for (int j = 0; j < FFF_NF4; ++j) nc1[j] = w2f4[r1 + j * 64];
#pragma unroll
            for (int j = 0; j < FFF_NF4; ++j) {
                a0[j] = na0[j]; a1[j] = na1[j];
                c0[j] = nc0[j]; c1[j] = nc1[j];
            }
        }
    }

    float4* __restrict__ of4 = (float4*)out;
    const int ob0 = b0 * FFF_ROWF4 + lane;
    const int ob1 = b1 * FFF_ROWF4 + lane;
#pragma unroll
    for (int j = 0; j < FFF_NF4; ++j) of4[ob0 + j * 64] = acc0[j];
#pragma unroll
    for (int j = 0; j < FFF_NF4; ++j) of4[ob1 + j * 64] = acc1[j];
}

extern "C" void kernel_launch(void* const* d_in, const int* in_sizes, int n_in,
                              void* d_out, int out_size, void* d_ws, size_t ws_size,
                              hipStream_t stream) {
    const float* x   = (const float*)d_in[0];
    const float* w1s = (const float*)d_in[1];
    const float* w2s = (const float*)d_in[2];
    float* out = (float*)d_out;

    const int B = out_size / FFF_D;            // 16384
    const int blocks = (B + 7) / 8;            // 4 waves x 2 samples per block

    fff_sparse_kernel<<<blocks, 256, 0, stream>>>(x, w1s, w2s, out, B);
}

// Round 4
// 319.309 us; speedup vs baseline: 1.0705x; 1.0705x over previous
//
#include <hip/hip_runtime.h>
#include <math.h>

// FFF sparse tree forward. B=16384, D_IN=D_OUT=768, DEPTH=11, n_nodes=4095.
//
// One wave per sample; lane owns 12 dims (3x float4, lane + j*64, coalesced).
// Per level: gather W1[node] row -> f64 dot (2 chains) -> f64 butterfly ->
// sign (readfirstlane -> scalar node) -> issue next W1 + this level's w2
// gathers -> exact-erf GELU + fma (off the serial chain).
//
// __launch_bounds__(256, 6): min 6 waves/EU -> VGPR budget 84 -> 24 waves/CU.
// R1 (120 VGPR, ~6 resident chains/CU) was latency-bound at VALUBusy 20%;
// ~14 chains/CU saturate VALU issue. R2/R3 showed the default allocator
// squeezing to 64 VGPR and spilling ~600 MB scratch — demand here is ~62
// VGPRs, safely under the 84 budget.

#define FFF_LVLS 12        // depth+1
#define FFF_D 768
#define FFF_NF4 3          // float4 per lane per row
#define FFF_ROWF4 192      // float4 per 768-f32 row

__device__ __forceinline__ float gelu_exact(float v) {
    return 0.5f * v * (1.0f + erff(v * 0.70710678118654752440f));
}

__global__ void __launch_bounds__(256, 6) fff_sparse_kernel(
    const float* __restrict__ x,
    const float* __restrict__ w1s,
    const float* __restrict__ w2s,
    float* __restrict__ out,
    int B)
{
    const int wave = threadIdx.x >> 6;
    const int lane = threadIdx.x & 63;
    const int b = blockIdx.x * 4 + wave;
    if (b >= B) return;

    const float4* __restrict__ xf4  = (const float4*)x;
    const float4* __restrict__ w1f4 = (const float4*)w1s;
    const float4* __restrict__ w2f4 = (const float4*)w2s;

    // x row in registers, coalesced.
    const int xb = b * FFF_ROWF4 + lane;
    float4 xv[FFF_NF4];
#pragma unroll
    for (int j = 0; j < FFF_NF4; ++j) xv[j] = xf4[xb + j * 64];

    float4 acc[FFF_NF4];
#pragma unroll
    for (int j = 0; j < FFF_NF4; ++j) acc[j] = make_float4(0.f, 0.f, 0.f, 0.f);

    // Prologue: root W1 + w2 rows.
    float4 a[FFF_NF4], c[FFF_NF4];
#pragma unroll
    for (int j = 0; j < FFF_NF4; ++j) a[j] = w1f4[lane + j * 64];
#pragma unroll
    for (int j = 0; j < FFF_NF4; ++j) c[j] = w2f4[lane + j * 64];

    int node = 0;   // wave-uniform scalar (sign readfirstlane'd)

#pragma unroll
    for (int lvl = 0; lvl < FFF_LVLS; ++lvl) {
        // Routing dot in f64 (sign matches exact sum), two chains for ILP.
        double p0 = 0.0, p1 = 0.0;
#pragma unroll
        for (int j = 0; j < FFF_NF4; ++j) {
            p0 += (double)xv[j].x * (double)a[j].x;
            p1 += (double)xv[j].y * (double)a[j].y;
            p0 += (double)xv[j].z * (double)a[j].z;
            p1 += (double)xv[j].w * (double)a[j].w;
        }
        double p = p0 + p1;
#pragma unroll
        for (int m = 32; m > 0; m >>= 1) p += __shfl_xor(p, m, 64);

        const int s = __builtin_amdgcn_readfirstlane(p >= 0.0 ? 1 : 0);
        const int prev = node;
        node = 2 * node + 1 + s;

        // Issue next level's latency-critical W1 gather immediately (a is
        // dead after the dot above), then the NEXT level's w2 row into c —
        // but first consume the CURRENT c with the fma below. Order of use:
        // c (fma, this iter) before a (dot, next iter): both in flight.
        const float act = gelu_exact((float)p);

        if (lvl + 1 < FFF_LVLS) {
            const int r = node * FFF_ROWF4 + lane;
#pragma unroll
            for (int j = 0; j < FFF_NF4; ++j) a[j] = w1f4[r + j * 64];
        }

        // Accumulate current level's w2 row (off the serial chain).
#pragma unroll
        for (int j = 0; j < FFF_NF4; ++j) {
            acc[j].x = fmaf(act, c[j].x, acc[j].x);
            acc[j].y = fmaf(act, c[j].y, acc[j].y);
            acc[j].z = fmaf(act, c[j].z, acc[j].z);
            acc[j].w = fmaf(act, c[j].w, acc[j].w);
        }

        // Load next level's w2 row (c now dead; a whole level of slack).
        if (lvl + 1 < FFF_LVLS) {
            const int r = node * FFF_ROWF4 + lane;
#pragma unroll
            for (int j = 0; j < FFF_NF4; ++j) c[j] = w2f4[r + j * 64];
        }
        (void)prev;
    }

    float4* __restrict__ of4 = (float4*)out;
    const int ob = b * FFF_ROWF4 + lane;
#pragma unroll
    for (int j = 0; j < FFF_NF4; ++j) of4[ob + j * 64] = acc[j];
}

extern "C" void kernel_launch(void* const* d_in, const int* in_sizes, int n_in,
                              void* d_out, int out_size, void* d_ws, size_t ws_size,
                              hipStream_t stream) {
    const float* x   = (const float*)d_in[0];
    const float* w1s = (const float*)d_in[1];
    const float* w2s = (const float*)d_in[2];
    float* out = (float*)d_out;

    const int B = out_size / FFF_D;            // 16384
    const int blocks = (B + 3) / 4;            // 4 waves (samples) per block

    fff_sparse_kernel<<<blocks, 256, 0, stream>>>(x, w1s, w2s, out, B);
}

// Round 5
// 75.136 us; speedup vs baseline: 4.5492x; 4.2498x over previous
//
#include <hip/hip_runtime.h>
#include <math.h>

// FFF sparse tree forward. B=16384, D_IN=D_OUT=768, DEPTH=11, n_nodes=4095.
//
// One wave per sample; lane owns 12 dims (3x float4, lane + j*64, coalesced).
//
// PHASE-SPLIT design (regalloc-driven, from R2-R4 post-mortems):
//   Phase 1 (tree walk): per level gather W1[node] row (loaded at loop top,
//     consumed immediately — the R1 idiom the allocator handles well),
//     f64 dot + f64 butterfly for exact-sum sign fidelity, record
//     act[lvl] = exact-erf GELU(logit) and the routing bit. Live set:
//     xv(12) + a(12) + acts(<=12) + scalars  ~= 44 VGPRs.
//   Phase 2 (accumulate): replay the node sequence from the bit mask; the 12
//     w2 row gathers depend only on a 3-op ALU chain, so they all issue
//     back-to-back and pipeline in the memory system. Live set: acts(12) +
//     acc(12) + c(12) ~= 40 VGPRs.
// Peak demand ~44 regs: no spill even if the allocator targets 64 VGPR /
// 8 waves per EU (R2/R3/R4 all collapsed into 600 MB scratch traffic when
// pipelined row registers pushed demand past the heuristic's budget).

#define FFF_LVLS 12        // depth+1
#define FFF_D 768
#define FFF_ROWF4 192      // float4 per 768-f32 row

__device__ __forceinline__ float gelu_exact(float v) {
    return 0.5f * v * (1.0f + erff(v * 0.70710678118654752440f));
}

__global__ void __launch_bounds__(256) fff_sparse_kernel(
    const float* __restrict__ x,
    const float* __restrict__ w1s,
    const float* __restrict__ w2s,
    float* __restrict__ out,
    int B)
{
    const int wave = threadIdx.x >> 6;
    const int lane = threadIdx.x & 63;
    const int b = blockIdx.x * 4 + wave;
    if (b >= B) return;

    const float4* __restrict__ xf4  = (const float4*)x;
    const float4* __restrict__ w1f4 = (const float4*)w1s;
    const float4* __restrict__ w2f4 = (const float4*)w2s;

    // x row in registers, coalesced.
    const int xb = b * FFF_ROWF4 + lane;
    const float4 xv0 = xf4[xb];
    const float4 xv1 = xf4[xb + 64];
    const float4 xv2 = xf4[xb + 128];

    // ---- Phase 1: tree walk. Only W1 touched; acts + routing bits recorded.
    float acts[FFF_LVLS];
    int bits = 0;
    int node = 0;   // per-lane (uniform value); R1 idiom — no readfirstlane

#pragma unroll
    for (int lvl = 0; lvl < FFF_LVLS; ++lvl) {
        const int r = node * FFF_ROWF4 + lane;
        const float4 a0 = w1f4[r];
        const float4 a1 = w1f4[r + 64];
        const float4 a2 = w1f4[r + 128];

        // f64 dot (sign matches exact sum), two chains for ILP.
        double p0 = (double)xv0.x * (double)a0.x;
        double p1 = (double)xv0.y * (double)a0.y;
        p0 += (double)xv0.z * (double)a0.z;
        p1 += (double)xv0.w * (double)a0.w;
        p0 += (double)xv1.x * (double)a1.x;
        p1 += (double)xv1.y * (double)a1.y;
        p0 += (double)xv1.z * (double)a1.z;
        p1 += (double)xv1.w * (double)a1.w;
        p0 += (double)xv2.x * (double)a2.x;
        p1 += (double)xv2.y * (double)a2.y;
        p0 += (double)xv2.z * (double)a2.z;
        p1 += (double)xv2.w * (double)a2.w;
        double p = p0 + p1;
#pragma unroll
        for (int m = 32; m > 0; m >>= 1) p += __shfl_xor(p, m, 64);

        acts[lvl] = gelu_exact((float)p);
        const int s = (p >= 0.0) ? 1 : 0;
        bits |= s << lvl;
        node = 2 * node + 1 + s;
    }

    // ---- Phase 2: w2 accumulation. 12 gathers chained only by 3-op ALU.
    float4 acc0 = make_float4(0.f, 0.f, 0.f, 0.f);
    float4 acc1 = make_float4(0.f, 0.f, 0.f, 0.f);
    float4 acc2 = make_float4(0.f, 0.f, 0.f, 0.f);

    node = 0;
#pragma unroll
    for (int lvl = 0; lvl < FFF_LVLS; ++lvl) {
        const int r = node * FFF_ROWF4 + lane;
        const float4 c0 = w2f4[r];
        const float4 c1 = w2f4[r + 64];
        const float4 c2 = w2f4[r + 128];
        const float a = acts[lvl];
        acc0.x = fmaf(a, c0.x, acc0.x);
        acc0.y = fmaf(a, c0.y, acc0.y);
        acc0.z = fmaf(a, c0.z, acc0.z);
        acc0.w = fmaf(a, c0.w, acc0.w);
        acc1.x = fmaf(a, c1.x, acc1.x);
        acc1.y = fmaf(a, c1.y, acc1.y);
        acc1.z = fmaf(a, c1.z, acc1.z);
        acc1.w = fmaf(a, c1.w, acc1.w);
        acc2.x = fmaf(a, c2.x, acc2.x);
        acc2.y = fmaf(a, c2.y, acc2.y);
        acc2.z = fmaf(a, c2.z, acc2.z);
        acc2.w = fmaf(a, c2.w, acc2.w);
        node = 2 * node + 1 + ((bits >> lvl) & 1);
    }

    float4* __restrict__ of4 = (float4*)out;
    const int ob = b * FFF_ROWF4 + lane;
    of4[ob]       = acc0;
    of4[ob + 64]  = acc1;
    of4[ob + 128] = acc2;
}

extern "C" void kernel_launch(void* const* d_in, const int* in_sizes, int n_in,
                              void* d_out, int out_size, void* d_ws, size_t ws_size,
                              hipStream_t stream) {
    const float* x   = (const float*)d_in[0];
    const float* w1s = (const float*)d_in[1];
    const float* w2s = (const float*)d_in[2];
    float* out = (float*)d_out;

    const int B = out_size / FFF_D;            // 16384
    const int blocks = (B + 3) / 4;            // 4 waves (samples) per block

    fff_sparse_kernel<<<blocks, 256, 0, stream>>>(x, w1s, w2s, out, B);
}

// Round 6
// 74.390 us; speedup vs baseline: 4.5948x; 1.0100x over previous
//
#include <hip/hip_runtime.h>
#include <math.h>

// FFF sparse tree forward. B=16384, D_IN=D_OUT=768, DEPTH=11, n_nodes=4095.
//
// One wave per TWO samples (interleaved chains), lane owns 12 dims of each
// row (3x float4 at lane + j*64, coalesced).
//
// R5 post-mortem: phase-split fixed the spill pathology (48 VGPR, clean) but
// phase 1 has ONE gather->f64dot->butterfly chain per wave -> latency-bound
// (VALU 27%, occ 46%, L2-fill 2.8 TB/s; nothing saturated). This round
// doubles per-wave MLP: two samples' chains interleave in phase 1. Register
// discipline (R2-R4 lesson: cross-iteration live ranges trigger the
// allocator's squeeze-and-spill): acts live in LDS (384 B/block), phase 2
// runs per-sample sequentially with a ~30-reg live set. Phase-1 peak ~58
// VGPRs -> no spill even at a 64-VGPR allocation.
//
// Tripwire: WRITE_SIZE must stay ~49 MB. If it jumps, scratch is back.

#define FFF_LVLS 12        // depth+1
#define FFF_D 768
#define FFF_ROWF4 192      // float4 per 768-f32 row

__device__ __forceinline__ float gelu_exact(float v) {
    return 0.5f * v * (1.0f + erff(v * 0.70710678118654752440f));
}

__global__ void __launch_bounds__(256) fff_sparse_kernel(
    const float* __restrict__ x,
    const float* __restrict__ w1s,
    const float* __restrict__ w2s,
    float* __restrict__ out,
    int B)
{
    __shared__ float s_actA[4][FFF_LVLS];
    __shared__ float s_actB[4][FFF_LVLS];

    const int wave = threadIdx.x >> 6;
    const int lane = threadIdx.x & 63;
    const int wid = blockIdx.x * 4 + wave;
    const int b0 = wid * 2;
    const int b1 = b0 + 1;
    if (b1 >= B) return;   // B even; grid sized exactly

    const float4* __restrict__ xf4  = (const float4*)x;
    const float4* __restrict__ w1f4 = (const float4*)w1s;
    const float4* __restrict__ w2f4 = (const float4*)w2s;

    // x rows in registers, coalesced.
    const int xbA = b0 * FFF_ROWF4 + lane;
    const int xbB = b1 * FFF_ROWF4 + lane;
    const float4 xa0 = xf4[xbA], xa1 = xf4[xbA + 64], xa2 = xf4[xbA + 128];
    const float4 xb0 = xf4[xbB], xb1 = xf4[xbB + 64], xb2 = xf4[xbB + 128];

    // ---- Phase 1: interleaved tree walks (two independent chains/wave).
    int bitsA = 0, bitsB = 0;
    int nodeA = 0, nodeB = 0;

#pragma unroll
    for (int lvl = 0; lvl < FFF_LVLS; ++lvl) {
        const int rA = nodeA * FFF_ROWF4 + lane;
        const int rB = nodeB * FFF_ROWF4 + lane;
        // Issue both samples' W1 gathers back-to-back (2 chains in flight).
        const float4 A0 = w1f4[rA], A1 = w1f4[rA + 64], A2 = w1f4[rA + 128];
        const float4 B0 = w1f4[rB], B1 = w1f4[rB + 64], B2 = w1f4[rB + 128];

        // f64 dots (sign matches exact sum); two chains per sample.
        double pa0 = (double)xa0.x * (double)A0.x;
        double pa1 = (double)xa0.y * (double)A0.y;
        pa0 += (double)xa0.z * (double)A0.z;
        pa1 += (double)xa0.w * (double)A0.w;
        pa0 += (double)xa1.x * (double)A1.x;
        pa1 += (double)xa1.y * (double)A1.y;
        pa0 += (double)xa1.z * (double)A1.z;
        pa1 += (double)xa1.w * (double)A1.w;
        pa0 += (double)xa2.x * (double)A2.x;
        pa1 += (double)xa2.y * (double)A2.y;
        pa0 += (double)xa2.z * (double)A2.z;
        pa1 += (double)xa2.w * (double)A2.w;

        double pb0 = (double)xb0.x * (double)B0.x;
        double pb1 = (double)xb0.y * (double)B0.y;
        pb0 += (double)xb0.z * (double)B0.z;
        pb1 += (double)xb0.w * (double)B0.w;
        pb0 += (double)xb1.x * (double)B1.x;
        pb1 += (double)xb1.y * (double)B1.y;
        pb0 += (double)xb1.z * (double)B1.z;
        pb1 += (double)xb1.w * (double)B1.w;
        pb0 += (double)xb2.x * (double)B2.x;
        pb1 += (double)xb2.y * (double)B2.y;
        pb0 += (double)xb2.z * (double)B2.z;
        pb1 += (double)xb2.w * (double)B2.w;

        double pa = pa0 + pa1;
        double pb = pb0 + pb1;
        // Interleaved butterflies: the two serial shfl chains overlap.
#pragma unroll
        for (int m = 32; m > 0; m >>= 1) {
            pa += __shfl_xor(pa, m, 64);
            pb += __shfl_xor(pb, m, 64);
        }

        if (lane == 0) {
            s_actA[wave][lvl] = gelu_exact((float)pa);
            s_actB[wave][lvl] = gelu_exact((float)pb);
        }
        const int sA = (pa >= 0.0) ? 1 : 0;
        const int sB = (pb >= 0.0) ? 1 : 0;
        bitsA |= sA << lvl;
        bitsB |= sB << lvl;
        nodeA = 2 * nodeA + 1 + sA;
        nodeB = 2 * nodeB + 1 + sB;
    }

    // ---- Phase 2: w2 accumulation, one sample at a time (lean live set;
    // 12 gathers per sample chained only through 3 cheap ALU ops).
    float4* __restrict__ of4 = (float4*)out;

    {
        float4 acc0 = make_float4(0.f, 0.f, 0.f, 0.f);
        float4 acc1 = make_float4(0.f, 0.f, 0.f, 0.f);
        float4 acc2 = make_float4(0.f, 0.f, 0.f, 0.f);
        int n = 0;
#pragma unroll
        for (int lvl = 0; lvl < FFF_LVLS; ++lvl) {
            const int r = n * FFF_ROWF4 + lane;
            const float4 c0 = w2f4[r];
            const float4 c1 = w2f4[r + 64];
            const float4 c2 = w2f4[r + 128];
            const float a = s_actA[wave][lvl];
            acc0.x = fmaf(a, c0.x, acc0.x); acc0.y = fmaf(a, c0.y, acc0.y);
            acc0.z = fmaf(a, c0.z, acc0.z); acc0.w = fmaf(a, c0.w, acc0.w);
            acc1.x = fmaf(a, c1.x, acc1.x); acc1.y = fmaf(a, c1.y, acc1.y);
            acc1.z = fmaf(a, c1.z, acc1.z); acc1.w = fmaf(a, c1.w, acc1.w);
            acc2.x = fmaf(a, c2.x, acc2.x); acc2.y = fmaf(a, c2.y, acc2.y);
            acc2.z = fmaf(a, c2.z, acc2.z); acc2.w = fmaf(a, c2.w, acc2.w);
            n = 2 * n + 1 + ((bitsA >> lvl) & 1);
        }
        const int ob = b0 * FFF_ROWF4 + lane;
        of4[ob] = acc0; of4[ob + 64] = acc1; of4[ob + 128] = acc2;
    }
    {
        float4 acc0 = make_float4(0.f, 0.f, 0.f, 0.f);
        float4 acc1 = make_float4(0.f, 0.f, 0.f, 0.f);
        float4 acc2 = make_float4(0.f, 0.f, 0.f, 0.f);
        int n = 0;
#pragma unroll
        for (int lvl = 0; lvl < FFF_LVLS; ++lvl) {
            const int r = n * FFF_ROWF4 + lane;
            const float4 c0 = w2f4[r];
            const float4 c1 = w2f4[r + 64];
            const float4 c2 = w2f4[r + 128];
            const float a = s_actB[wave][lvl];
            acc0.x = fmaf(a, c0.x, acc0.x); acc0.y = fmaf(a, c0.y, acc0.y);
            acc0.z = fmaf(a, c0.z, acc0.z); acc0.w = fmaf(a, c0.w, acc0.w);
            acc1.x = fmaf(a, c1.x, acc1.x); acc1.y = fmaf(a, c1.y, acc1.y);
            acc1.z = fmaf(a, c1.z, acc1.z); acc1.w = fmaf(a, c1.w, acc1.w);
            acc2.x = fmaf(a, c2.x, acc2.x); acc2.y = fmaf(a, c2.y, acc2.y);
            acc2.z = fmaf(a, c2.z, acc2.z); acc2.w = fmaf(a, c2.w, acc2.w);
            n = 2 * n + 1 + ((bitsB >> lvl) & 1);
        }
        const int ob = b1 * FFF_ROWF4 + lane;
        of4[ob] = acc0; of4[ob + 64] = acc1; of4[ob + 128] = acc2;
    }
}

extern "C" void kernel_launch(void* const* d_in, const int* in_sizes, int n_in,
                              void* d_out, int out_size, void* d_ws, size_t ws_size,
                              hipStream_t stream) {
    const float* x   = (const float*)d_in[0];
    const float* w1s = (const float*)d_in[1];
    const float* w2s = (const float*)d_in[2];
    float* out = (float*)d_out;

    const int B = out_size / FFF_D;            // 16384
    const int blocks = (B + 7) / 8;            // 4 waves x 2 samples per block

    fff_sparse_kernel<<<blocks, 256, 0, stream>>>(x, w1s, w2s, out, B);
}

// Round 9
// 72.972 us; speedup vs baseline: 4.6841x; 1.0194x over previous
//
#include <hip/hip_runtime.h>
#include <math.h>

// FFF sparse tree forward. B=16384, D_IN=D_OUT=768, DEPTH=11, n_nodes=4095.
//
// One wave per sample; lane owns 12 dims (3x float4 at lane + j*64).
// Phase-split (R5 structure, 48 VGPR, no spill):
//   Phase 1: tree walk. Per level: gather W1[node] row -> f32 dot (2 chains)
//     -> DPP wave64 reduce (pure VALU, compiler-managed hazards) -> sign +
//     exact-erf GELU recorded. If |p_f32| < 1e-4 (prob ~2e-4), sign is
//     ambiguous at f32 precision -> rare wave-uniform f64 recompute (dot +
//     shfl butterfly) so routing matches the f64 numpy reference.
//   Phase 2: replay node sequence from bit mask; 12 independent w2 row
//     gathers + f32 fma; coalesced float4 store.
//
// R8 post-mortem: update_dpp's ctrl operand must be an immediate -> template
// parameter (compile-time constant), otherwise identical to R8's design.

#define FFF_LVLS 12        // depth+1
#define FFF_D 768
#define FFF_ROWF4 192      // float4 per 768-f32 row

__device__ __forceinline__ float gelu_exact(float v) {
    return 0.5f * v * (1.0f + erff(v * 0.70710678118654752440f));
}

// v += (v shifted right by N lanes within each 16-lane row); OOB lanes read 0
// (bound_ctrl=true). Compiler inserts the required DPP hazard wait-states.
template <int CTRL>
__device__ __forceinline__ float dpp_shr_add(float v) {
    const int t = __builtin_amdgcn_update_dpp(
        0, __builtin_bit_cast(int, v), CTRL, 0xf, 0xf, true);
    return v + __builtin_bit_cast(float, t);
}

// Wave64 sum, pure VALU. After 4 row_shr steps lane 0 of each 16-lane row
// holds that row's sum... (row_shr moves data toward LOWER lanes reading
// from higher? No: row_shr:N means lane i reads lane i-N; with bound_ctrl
// OOB=0. So partial sums accumulate toward HIGHER lanes; lane 15/31/47/63
// hold each row's total.) Readlane those four + 3 adds -> wave-uniform sum.
__device__ __forceinline__ float wave_allsum_f32(float v) {
    v = dpp_shr_add<0x111>(v);   // row_shr:1  (lane i += lane i-1)
    v = dpp_shr_add<0x112>(v);   // row_shr:2
    v = dpp_shr_add<0x114>(v);   // row_shr:4
    v = dpp_shr_add<0x118>(v);   // row_shr:8
    const int i15 = __builtin_amdgcn_readlane(__builtin_bit_cast(int, v), 15);
    const int i31 = __builtin_amdgcn_readlane(__builtin_bit_cast(int, v), 31);
    const int i47 = __builtin_amdgcn_readlane(__builtin_bit_cast(int, v), 47);
    const int i63 = __builtin_amdgcn_readlane(__builtin_bit_cast(int, v), 63);
    return (__builtin_bit_cast(float, i15) + __builtin_bit_cast(float, i31))
         + (__builtin_bit_cast(float, i47) + __builtin_bit_cast(float, i63));
}

__global__ void __launch_bounds__(256) fff_sparse_kernel(
    const float* __restrict__ x,
    const float* __restrict__ w1s,
    const float* __restrict__ w2s,
    float* __restrict__ out,
    int B)
{
    const int wave = threadIdx.x >> 6;
    const int lane = threadIdx.x & 63;
    const int b = blockIdx.x * 4 + wave;
    if (b >= B) return;

    const float4* __restrict__ xf4  = (const float4*)x;
    const float4* __restrict__ w1f4 = (const float4*)w1s;
    const float4* __restrict__ w2f4 = (const float4*)w2s;

    // x row in registers, coalesced.
    const int xb = b * FFF_ROWF4 + lane;
    const float4 xv0 = xf4[xb];
    const float4 xv1 = xf4[xb + 64];
    const float4 xv2 = xf4[xb + 128];

    // ---- Phase 1: tree walk (W1 only; acts + routing bits recorded).
    float acts[FFF_LVLS];
    int bits = 0;
    int node = 0;

#pragma unroll
    for (int lvl = 0; lvl < FFF_LVLS; ++lvl) {
        const int r = node * FFF_ROWF4 + lane;
        const float4 a0 = w1f4[r];
        const float4 a1 = w1f4[r + 64];
        const float4 a2 = w1f4[r + 128];

        // f32 dot, two chains.
        float q0 = xv0.x * a0.x;
        float q1 = xv0.y * a0.y;
        q0 = fmaf(xv0.z, a0.z, q0);
        q1 = fmaf(xv0.w, a0.w, q1);
        q0 = fmaf(xv1.x, a1.x, q0);
        q1 = fmaf(xv1.y, a1.y, q1);
        q0 = fmaf(xv1.z, a1.z, q0);
        q1 = fmaf(xv1.w, a1.w, q1);
        q0 = fmaf(xv2.x, a2.x, q0);
        q1 = fmaf(xv2.y, a2.y, q1);
        q0 = fmaf(xv2.z, a2.z, q0);
        q1 = fmaf(xv2.w, a2.w, q1);

        float p = wave_allsum_f32(q0 + q1);   // wave-uniform

        // Rare wave-uniform fallback: f32 sum error ~1e-6, so only
        // |p| < 1e-4 can have an f32/f64 sign discrepancy (~2e-4 of levels).
        if (__builtin_expect(fabsf(p) < 1e-4f, 0)) {
            double d0 = (double)xv0.x * (double)a0.x;
            double d1 = (double)xv0.y * (double)a0.y;
            d0 += (double)xv0.z * (double)a0.z;
            d1 += (double)xv0.w * (double)a0.w;
            d0 += (double)xv1.x * (double)a1.x;
            d1 += (double)xv1.y * (double)a1.y;
            d0 += (double)xv1.z * (double)a1.z;
            d1 += (double)xv1.w * (double)a1.w;
            d0 += (double)xv2.x * (double)a2.x;
            d1 += (double)xv2.y * (double)a2.y;
            d0 += (double)xv2.z * (double)a2.z;
            d1 += (double)xv2.w * (double)a2.w;
            double pd = d0 + d1;
#pragma unroll
            for (int m = 32; m > 0; m >>= 1) pd += __shfl_xor(pd, m, 64);
            p = (float)pd;
        }

        acts[lvl] = gelu_exact(p);
        const int s = (p >= 0.0f) ? 1 : 0;
        bits |= s << lvl;
        node = 2 * node + 1 + s;
    }

    // ---- Phase 2: w2 accumulation (12 gathers, 3-op ALU chain only).
    float4 acc0 = make_float4(0.f, 0.f, 0.f, 0.f);
    float4 acc1 = make_float4(0.f, 0.f, 0.f, 0.f);
    float4 acc2 = make_float4(0.f, 0.f, 0.f, 0.f);

    node = 0;
#pragma unroll
    for (int lvl = 0; lvl < FFF_LVLS; ++lvl) {
        const int r = node * FFF_ROWF4 + lane;
        const float4 c0 = w2f4[r];
        const float4 c1 = w2f4[r + 64];
        const float4 c2 = w2f4[r + 128];
        const float a = acts[lvl];
        acc0.x = fmaf(a, c0.x, acc0.x); acc0.y = fmaf(a, c0.y, acc0.y);
        acc0.z = fmaf(a, c0.z, acc0.z); acc0.w = fmaf(a, c0.w, acc0.w);
        acc1.x = fmaf(a, c1.x, acc1.x); acc1.y = fmaf(a, c1.y, acc1.y);
        acc1.z = fmaf(a, c1.z, acc1.z); acc1.w = fmaf(a, c1.w, acc1.w);
        acc2.x = fmaf(a, c2.x, acc2.x); acc2.y = fmaf(a, c2.y, acc2.y);
        acc2.z = fmaf(a, c2.z, acc2.z); acc2.w = fmaf(a, c2.w, acc2.w);
        node = 2 * node + 1 + ((bits >> lvl) & 1);
    }

    float4* __restrict__ of4 = (float4*)out;
    const int ob = b * FFF_ROWF4 + lane;
    of4[ob]       = acc0;
    of4[ob + 64]  = acc1;
    of4[ob + 128] = acc2;
}

extern "C" void kernel_launch(void* const* d_in, const int* in_sizes, int n_in,
                              void* d_out, int out_size, void* d_ws, size_t ws_size,
                              hipStream_t stream) {
    const float* x   = (const float*)d_in[0];
    const float* w1s = (const float*)d_in[1];
    const float* w2s = (const float*)d_in[2];
    float* out = (float*)d_out;

    const int B = out_size / FFF_D;            // 16384
    const int blocks = (B + 3) / 4;            // 4 waves (samples) per block

    fff_sparse_kernel<<<blocks, 256, 0, stream>>>(x, w1s, w2s, out, B);
}